// Round 1
// 1297.083 us; speedup vs baseline: 1.1516x; 1.1516x over previous
//
#include <hip/hip_runtime.h>
#include <hip/hip_bf16.h>

#define BB 16
#define SS 4096
#define EE 128
#define DMM 64
#define HH_ 8
#define FFF 256
#define LLAY 8
#define CC 1623
#define NTOK (BB*SS)
#define NSPLIT 4

typedef __attribute__((ext_vector_type(8))) short bf8v;   // 8 bf16
typedef __attribute__((ext_vector_type(4))) float f4;

__device__ __forceinline__ f4 MFMA(bf8v a, bf8v b, f4 c) {
  return __builtin_amdgcn_mfma_f32_16x16x32_bf16(a, b, c, 0, 0, 0);
}

__device__ __forceinline__ float bf2f(ushort u) {
  union { uint i; float f; } x; x.i = (uint)u << 16; return x.f;
}
__device__ __forceinline__ ushort f2bf(float f) {
  union { float f; uint i; } x; x.f = f;
  return (ushort)((x.i + 0x7fffu + ((x.i >> 16) & 1u)) >> 16);   // RNE
}

__device__ __forceinline__ void wave_stats(float v, float& mean, float& var) {
  float s = v, s2 = v * v;
  #pragma unroll
  for (int m = 32; m; m >>= 1) {
    s  += __shfl_xor(s,  m, 64);
    s2 += __shfl_xor(s2, m, 64);
  }
  mean = s * (1.0f / 64.0f);
  var  = s2 * (1.0f / 64.0f) - mean * mean;
}

__device__ __forceinline__ float gelu_tanh(float x) {
  float u = 0.7978845608028654f * (x + 0.044715f * x * x * x);
  float t = 1.0f - 2.0f / (__expf(2.0f * u) + 1.0f);
  return 0.5f * x * (1.0f + t);
}
__device__ __forceinline__ float phi_elu(float x) { return x > 0.0f ? x + 1.0f : __expf(x); }

// ---------------------------------------------------------------------------
// W[K][N] fp32 -> Wt[N][K] bf16 (batched over gridDim.y layers)
// ---------------------------------------------------------------------------
__global__ __launch_bounds__(256) void k_convT(
    const float* __restrict__ W, ushort* __restrict__ Wt, int K, int N)
{
  const size_t base = (size_t)blockIdx.y * K * N;
  int idx = blockIdx.x * 256 + threadIdx.x;
  if (idx >= K * N) return;
  int k = idx / N, n = idx - k * N;
  Wt[base + (size_t)n * K + k] = f2bf(W[base + idx]);
}

// ---------------------------------------------------------------------------
// hh = (ex@we + be + lemb[labels]) @ w_in + b_in   (64 tokens / block)
// ---------------------------------------------------------------------------
__global__ __launch_bounds__(512) void k_embed(
    const float* __restrict__ ex, const int* __restrict__ labels,
    const ushort* __restrict__ wet, const float* __restrict__ be,
    const float* __restrict__ lemb, const ushort* __restrict__ wint,
    const float* __restrict__ b_in, float* __restrict__ hh)
{
  __shared__ ushort exL[64][136];
  __shared__ ushort embL[64][136];
  __shared__ int labL[64];
  const int tid = threadIdx.x, lane = tid & 63, w = tid >> 6;
  const int t0 = blockIdx.x * 64;

  if (tid < 64) labL[tid] = labels[t0 + tid];
  #pragma unroll
  for (int i = 0; i < 16; ++i) {
    int idx = tid + 512 * i;
    int t = idx >> 7, k = idx & 127;
    exL[t][k] = f2bf(ex[(size_t)(t0 + t) * EE + k]);
  }
  __syncthreads();

  const int col = lane & 15, quad = lane >> 4;
  const int m0 = (w >> 1) * 16, nh = w & 1;

  {
    bf8v a[4];
    #pragma unroll
    for (int kf = 0; kf < 4; ++kf)
      a[kf] = *(const bf8v*)&exL[m0 + col][kf * 32 + quad * 8];
    #pragma unroll
    for (int nt = 0; nt < 4; ++nt) {
      int n0 = nh * 64 + nt * 16;
      const ushort* bp = wet + (size_t)(n0 + col) * 128 + quad * 8;
      f4 acc = {0.f, 0.f, 0.f, 0.f};
      #pragma unroll
      for (int kf = 0; kf < 4; ++kf)
        acc = MFMA(a[kf], *(const bf8v*)(bp + kf * 32), acc);
      int c = n0 + col;
      float bev = be[c];
      #pragma unroll
      for (int r = 0; r < 4; ++r) {
        int tl = m0 + quad * 4 + r;
        embL[tl][c] = f2bf(acc[r] + bev + lemb[(size_t)labL[tl] * EE + c]);
      }
    }
  }
  __syncthreads();

  {
    bf8v a[4];
    #pragma unroll
    for (int kf = 0; kf < 4; ++kf)
      a[kf] = *(const bf8v*)&embL[m0 + col][kf * 32 + quad * 8];
    #pragma unroll
    for (int nt = 0; nt < 2; ++nt) {
      int n0 = nh * 32 + nt * 16;
      const ushort* bp = wint + (size_t)(n0 + col) * 128 + quad * 8;
      f4 acc = {0.f, 0.f, 0.f, 0.f};
      #pragma unroll
      for (int kf = 0; kf < 4; ++kf)
        acc = MFMA(a[kf], *(const bf8v*)(bp + kf * 32), acc);
      int c = n0 + col;
      float biv = b_in[c];
      #pragma unroll
      for (int r = 0; r < 4; ++r) {
        int tl = m0 + quad * 4 + r;
        hh[(size_t)(t0 + tl) * DMM + c] = acc[r] + biv;
      }
    }
  }
}

// ---------------------------------------------------------------------------
// x = LN1(mask*hh); pq=phi(x@wq+bq), pk=phi(x@wk+bk)*mask, vv=x@wv+bv  (bf16)
// ---------------------------------------------------------------------------
__global__ __launch_bounds__(512) void k_pre(
    const float* __restrict__ hh, const float* __restrict__ mask,
    const float* __restrict__ g1, const float* __restrict__ b1,
    const ushort* __restrict__ wqt, const float* __restrict__ bq,
    const ushort* __restrict__ wkt, const float* __restrict__ bk,
    const ushort* __restrict__ wvt, const float* __restrict__ bv,
    ushort* __restrict__ pq, ushort* __restrict__ pk, ushort* __restrict__ vv)
{
  __shared__ ushort xbf[64][72];
  __shared__ float mk[64];
  const int tid = threadIdx.x, lane = tid & 63, w = tid >> 6;
  const int t0 = blockIdx.x * 64;

  #pragma unroll
  for (int m = 0; m < 8; ++m) {
    int t = w * 8 + m;
    float mv = mask[t0 + t];
    float v = hh[(size_t)(t0 + t) * DMM + lane] * mv;
    float mean, var; wave_stats(v, mean, var);
    xbf[t][lane] = f2bf((v - mean) * rsqrtf(var + 1e-5f) * g1[lane] + b1[lane]);
    if (lane == 0) mk[t] = mv;
  }
  __syncthreads();

  const int col = lane & 15, quad = lane >> 4;
  const int m0 = (w >> 1) * 16, nh = w & 1;

  bf8v a0 = *(const bf8v*)&xbf[m0 + col][quad * 8];
  bf8v a1 = *(const bf8v*)&xbf[m0 + col][32 + quad * 8];

  f4 accq[2], acck[2], accv[2];
  #pragma unroll
  for (int nt = 0; nt < 2; ++nt) {
    int nr = nh * 32 + nt * 16 + col;
    const ushort* bpq = wqt + (size_t)nr * 64 + quad * 8;
    const ushort* bpk = wkt + (size_t)nr * 64 + quad * 8;
    const ushort* bpv = wvt + (size_t)nr * 64 + quad * 8;
    f4 z = {0.f, 0.f, 0.f, 0.f};
    accq[nt] = MFMA(a1, *(const bf8v*)(bpq + 32), MFMA(a0, *(const bf8v*)bpq, z));
    acck[nt] = MFMA(a1, *(const bf8v*)(bpk + 32), MFMA(a0, *(const bf8v*)bpk, z));
    accv[nt] = MFMA(a1, *(const bf8v*)(bpv + 32), MFMA(a0, *(const bf8v*)bpv, z));
  }
  #pragma unroll
  for (int nt = 0; nt < 2; ++nt) {
    int c = nh * 32 + nt * 16 + col;
    float bqv = bq[c], bkv = bk[c], bvv = bv[c];
    #pragma unroll
    for (int r = 0; r < 4; ++r) {
      int tl = m0 + quad * 4 + r;
      size_t o = (size_t)(t0 + tl) * DMM + c;
      pq[o] = f2bf(phi_elu(accq[nt][r] + bqv));
      pk[o] = f2bf(phi_elu(acck[nt][r] + bkv) * mk[tl]);
      vv[o] = f2bf(accv[nt][r] + bvv);
    }
  }
}

// ---------------------------------------------------------------------------
// kv/ksum partials per (b,h,split)
// ---------------------------------------------------------------------------
__global__ __launch_bounds__(256) void k_kv(
    const ushort* __restrict__ pk, const ushort* __restrict__ vv,
    float* __restrict__ part)
{
  const int bh = blockIdx.x / NSPLIT, sp = blockIdx.x % NSPLIT;
  const int b = bh >> 3, h = bh & 7;
  const int tid = threadIdx.x, lane = tid & 63, w = tid >> 6;

  float kv[8][8], ks[8];
  #pragma unroll
  for (int d = 0; d < 8; ++d) {
    ks[d] = 0.f;
    #pragma unroll
    for (int e = 0; e < 8; ++e) kv[d][e] = 0.f;
  }

  const int sbase = sp * (SS / NSPLIT) + w * (SS / NSPLIT / 4);
  for (int it = 0; it < SS / NSPLIT / 4 / 64; ++it) {
    int s = sbase + it * 64 + lane;
    size_t o = ((size_t)b * SS + s) * DMM + h * 8;
    bf8v pv = *(const bf8v*)(pk + o);
    bf8v uv = *(const bf8v*)(vv + o);
    float p[8], u[8];
    #pragma unroll
    for (int i = 0; i < 8; ++i) { p[i] = bf2f((ushort)pv[i]); u[i] = bf2f((ushort)uv[i]); }
    #pragma unroll
    for (int d = 0; d < 8; ++d) {
      ks[d] += p[d];
      #pragma unroll
      for (int e = 0; e < 8; ++e) kv[d][e] += p[d] * u[e];
    }
  }

  #pragma unroll
  for (int mk = 32; mk; mk >>= 1) {
    #pragma unroll
    for (int d = 0; d < 8; ++d) {
      ks[d] += __shfl_xor(ks[d], mk, 64);
      #pragma unroll
      for (int e = 0; e < 8; ++e) kv[d][e] += __shfl_xor(kv[d][e], mk, 64);
    }
  }

  __shared__ float red[4][72];
  if (lane == 0) {
    #pragma unroll
    for (int d = 0; d < 8; ++d) {
      red[w][64 + d] = ks[d];
      #pragma unroll
      for (int e = 0; e < 8; ++e) red[w][d * 8 + e] = kv[d][e];
    }
  }
  __syncthreads();
  if (tid < 72) {
    float s = red[0][tid] + red[1][tid] + red[2][tid] + red[3][tid];
    part[(size_t)blockIdx.x * 72 + tid] = s;
  }
}

// ---------------------------------------------------------------------------
// att = (pq@kv)/(pq.ksum+eps); hh = mask*hh + att@wo + bo;
// y = LN2(hh); hh += gelu(y@w1+b1)@w2 + b2     (64 tokens / block)
// ---------------------------------------------------------------------------
__global__ __launch_bounds__(512) void k_post(
    float* __restrict__ hh, const float* __restrict__ mask,
    const float* __restrict__ part, const ushort* __restrict__ pq,
    const ushort* __restrict__ wot, const float* __restrict__ bo,
    const float* __restrict__ g2, const float* __restrict__ b2ln,
    const ushort* __restrict__ w1t, const float* __restrict__ b1f,
    const ushort* __restrict__ w2t, const float* __restrict__ b2f)
{
  __shared__ union UU {
    struct { float pqL[64][64]; ushort attbf[64][72]; } a;
    ushort tfL[64][264];
  } U;
  __shared__ float hhL[64][64];
  __shared__ ushort ybf[64][72];
  __shared__ float kvL[8][72];

  const int tid = threadIdx.x, lane = tid & 63, w = tid >> 6;
  const int t0 = blockIdx.x * 64;
  const int b = t0 >> 12;

  for (int r = tid; r < 576; r += 512) {
    int h = r / 72, rr = r - h * 72;
    const float* pp = part + (size_t)(b * HH_ + h) * (NSPLIT * 72) + rr;
    kvL[h][rr] = pp[0] + pp[72] + pp[144] + pp[216];
  }
  #pragma unroll
  for (int i = 0; i < 8; ++i) {
    int idx = tid + 512 * i;
    int t = idx >> 6, k = idx & 63;
    U.a.pqL[t][k] = bf2f(pq[(size_t)(t0 + t) * DMM + k]);
    hhL[t][k] = hh[(size_t)(t0 + t) * DMM + k] * mask[t0 + t];
  }
  __syncthreads();

  {
    const int j = lane, h = j >> 3, e = j & 7;
    #pragma unroll
    for (int m = 0; m < 8; ++m) {
      int t = w * 8 + m;
      float num = 0.f, den = 1e-6f;
      #pragma unroll
      for (int d = 0; d < 8; ++d) {
        float p = U.a.pqL[t][h * 8 + d];
        num += p * kvL[h][d * 8 + e];
        den += p * kvL[h][64 + d];
      }
      U.a.attbf[t][j] = f2bf(num / den);
    }
  }
  __syncthreads();

  const int col = lane & 15, quad = lane >> 4;
  const int m0 = (w >> 1) * 16, nh = w & 1;

  // att @ wo + residual -> hhL
  {
    bf8v a0 = *(const bf8v*)&U.a.attbf[m0 + col][quad * 8];
    bf8v a1 = *(const bf8v*)&U.a.attbf[m0 + col][32 + quad * 8];
    #pragma unroll
    for (int nt = 0; nt < 2; ++nt) {
      int c = nh * 32 + nt * 16 + col;
      const ushort* bp = wot + (size_t)c * 64 + quad * 8;
      f4 z = {0.f, 0.f, 0.f, 0.f};
      f4 acc = MFMA(a1, *(const bf8v*)(bp + 32), MFMA(a0, *(const bf8v*)bp, z));
      float bov = bo[c];
      #pragma unroll
      for (int r = 0; r < 4; ++r) {
        int tl = m0 + quad * 4 + r;
        hhL[tl][c] += acc[r] + bov;
      }
    }
  }
  __syncthreads();

  // LN2
  #pragma unroll
  for (int m = 0; m < 8; ++m) {
    int t = w * 8 + m;
    float v = hhL[t][lane];
    float mean, var; wave_stats(v, mean, var);
    ybf[t][lane] = f2bf((v - mean) * rsqrtf(var + 1e-5f) * g2[lane] + b2ln[lane]);
  }
  __syncthreads();

  // FFN1 + gelu -> tfL (clobbers pqL/attbf: safe, last read before prev sync)
  {
    bf8v a0 = *(const bf8v*)&ybf[m0 + col][quad * 8];
    bf8v a1 = *(const bf8v*)&ybf[m0 + col][32 + quad * 8];
    #pragma unroll
    for (int nt = 0; nt < 8; ++nt) {
      int c = nh * 128 + nt * 16 + col;
      const ushort* bp = w1t + (size_t)c * 64 + quad * 8;
      f4 z = {0.f, 0.f, 0.f, 0.f};
      f4 acc = MFMA(a1, *(const bf8v*)(bp + 32), MFMA(a0, *(const bf8v*)bp, z));
      float b1v = b1f[c];
      #pragma unroll
      for (int r = 0; r < 4; ++r)
        U.tfL[m0 + quad * 4 + r][c] = f2bf(gelu_tanh(acc[r] + b1v));
    }
  }
  __syncthreads();

  // FFN2 + residual -> hh
  {
    bf8v af[8];
    #pragma unroll
    for (int kf = 0; kf < 8; ++kf)
      af[kf] = *(const bf8v*)&U.tfL[m0 + col][kf * 32 + quad * 8];
    #pragma unroll
    for (int nt = 0; nt < 2; ++nt) {
      int c = nh * 32 + nt * 16 + col;
      const ushort* bp = w2t + (size_t)c * 256 + quad * 8;
      f4 acc = {0.f, 0.f, 0.f, 0.f};
      #pragma unroll
      for (int kf = 0; kf < 8; ++kf)
        acc = MFMA(af[kf], *(const bf8v*)(bp + kf * 32), acc);
      float b2v = b2f[c];
      #pragma unroll
      for (int r = 0; r < 4; ++r) {
        int tl = m0 + quad * 4 + r;
        hh[(size_t)(t0 + tl) * DMM + c] = hhL[tl][c] + acc[r] + b2v;
      }
    }
  }
}

// ---------------------------------------------------------------------------
// out = (LNf(hh)*mask) @ wout + bout   (64 tokens / block)
// LDS-staged epilogue: MFMA tiles -> outL[64][128-chunk] -> row-major
// wave-contiguous 256B stores (fixes scattered/misaligned 64B store segments)
// ---------------------------------------------------------------------------
__global__ __launch_bounds__(512) void k_final(
    const float* __restrict__ hh, const float* __restrict__ mask,
    const float* __restrict__ gf, const float* __restrict__ bfn,
    const ushort* __restrict__ woutt, const float* __restrict__ bout,
    float* __restrict__ out)
{
  __shared__ ushort xbf[64][72];
  __shared__ float outL[64][132];   // stride 132: quad rows land 2-way (free)
  const int tid = threadIdx.x, lane = tid & 63, w = tid >> 6;
  const int t0 = blockIdx.x * 64;

  #pragma unroll
  for (int m = 0; m < 8; ++m) {
    int t = w * 8 + m;
    float v = hh[(size_t)(t0 + t) * DMM + lane];
    float mean, var; wave_stats(v, mean, var);
    xbf[t][lane] = f2bf(((v - mean) * rsqrtf(var + 1e-5f) * gf[lane] + bfn[lane]) * mask[t0 + t]);
  }
  __syncthreads();

  const int col = lane & 15, quad = lane >> 4;
  bf8v a0[4], a1[4];
  #pragma unroll
  for (int mt = 0; mt < 4; ++mt) {
    a0[mt] = *(const bf8v*)&xbf[mt * 16 + col][quad * 8];
    a1[mt] = *(const bf8v*)&xbf[mt * 16 + col][32 + quad * 8];
  }

  // 102 column-tiles of 16; process 8 tiles (128 cols) per group, 13 groups
  for (int g = 0; g < 13; ++g) {
    int tile = g * 8 + w;
    if (tile < 102) {
      int c = tile * 16 + col;
      int cr = c < CC ? c : CC - 1;
      const ushort* bp = woutt + (size_t)cr * 64 + quad * 8;
      bf8v b0 = *(const bf8v*)bp;
      bf8v b1 = *(const bf8v*)(bp + 32);
      float bov = bout[cr];
      #pragma unroll
      for (int mt = 0; mt < 4; ++mt) {
        f4 z = {0.f, 0.f, 0.f, 0.f};
        f4 acc = MFMA(a1[mt], b1, MFMA(a0[mt], b0, z));
        #pragma unroll
        for (int r = 0; r < 4; ++r)
          outL[mt * 16 + quad * 4 + r][w * 16 + col] = acc[r] + bov;
      }
    }
    __syncthreads();

    const int c0 = g * 128;
    int nc = CC - c0; if (nc > 128) nc = 128;
    // 512 threads copy 64 x nc floats; each wave-store = 64 consecutive
    // floats of one row = 256B contiguous
    #pragma unroll
    for (int it = 0; it < 16; ++it) {
      int idx = tid + it * 512;
      int row = idx >> 7, cc = idx & 127;
      if (cc < nc)
        out[(size_t)(t0 + row) * CC + c0 + cc] = outL[row][cc];
    }
    __syncthreads();
  }
}

// ---------------------------------------------------------------------------

extern "C" void kernel_launch(void* const* d_in, const int* in_sizes, int n_in,
                              void* d_out, int out_size, void* d_ws, size_t ws_size,
                              hipStream_t stream) {
  (void)in_sizes; (void)n_in; (void)out_size; (void)ws_size;
  const float* ex    = (const float*)d_in[0];
  const int*   labels= (const int*)  d_in[1];
  const float* mask  = (const float*)d_in[2];
  const float* we    = (const float*)d_in[3];
  const float* be    = (const float*)d_in[4];
  const float* lemb  = (const float*)d_in[5];
  const float* w_in  = (const float*)d_in[6];
  const float* b_in  = (const float*)d_in[7];
  const float* ln1s  = (const float*)d_in[8];
  const float* ln1b  = (const float*)d_in[9];
  const float* wq    = (const float*)d_in[10];
  const float* bq    = (const float*)d_in[11];
  const float* wk    = (const float*)d_in[12];
  const float* bk    = (const float*)d_in[13];
  const float* wv    = (const float*)d_in[14];
  const float* bv    = (const float*)d_in[15];
  const float* wo    = (const float*)d_in[16];
  const float* bo    = (const float*)d_in[17];
  const float* ln2s  = (const float*)d_in[18];
  const float* ln2b  = (const float*)d_in[19];
  const float* w1    = (const float*)d_in[20];
  const float* b1    = (const float*)d_in[21];
  const float* w2    = (const float*)d_in[22];
  const float* b2    = (const float*)d_in[23];
  const float* lnfs  = (const float*)d_in[24];
  const float* lnfb  = (const float*)d_in[25];
  const float* wout  = (const float*)d_in[26];
  const float* bout  = (const float*)d_in[27];

  char* p = (char*)d_ws;
  float*  hh   = (float*)p;  p += (size_t)NTOK * DMM * 4;
  ushort* pqb  = (ushort*)p; p += (size_t)NTOK * DMM * 2;
  ushort* pkb  = (ushort*)p; p += (size_t)NTOK * DMM * 2;
  ushort* vvb  = (ushort*)p; p += (size_t)NTOK * DMM * 2;
  float*  part = (float*)p;  p += (size_t)BB * HH_ * NSPLIT * 72 * 4;
  ushort* wet  = (ushort*)p; p += 128 * 128 * 2;
  ushort* wint = (ushort*)p; p += 64 * 128 * 2;
  ushort* wqt  = (ushort*)p; p += (size_t)LLAY * 64 * 64 * 2;
  ushort* wkt  = (ushort*)p; p += (size_t)LLAY * 64 * 64 * 2;
  ushort* wvt  = (ushort*)p; p += (size_t)LLAY * 64 * 64 * 2;
  ushort* wot  = (ushort*)p; p += (size_t)LLAY * 64 * 64 * 2;
  ushort* w1t  = (ushort*)p; p += (size_t)LLAY * 64 * 256 * 2;
  ushort* w2t  = (ushort*)p; p += (size_t)LLAY * 256 * 64 * 2;
  ushort* woutt= (ushort*)p; p += (size_t)64 * CC * 2;

  // weight conversions (bf16, transposed [n][k])
  k_convT<<<dim3(64, 1),  256, 0, stream>>>(we,   wet,  128, 128);
  k_convT<<<dim3(32, 1),  256, 0, stream>>>(w_in, wint, 128, 64);
  k_convT<<<dim3(16, LLAY), 256, 0, stream>>>(wq, wqt, 64, 64);
  k_convT<<<dim3(16, LLAY), 256, 0, stream>>>(wk, wkt, 64, 64);
  k_convT<<<dim3(16, LLAY), 256, 0, stream>>>(wv, wvt, 64, 64);
  k_convT<<<dim3(16, LLAY), 256, 0, stream>>>(wo, wot, 64, 64);
  k_convT<<<dim3(64, LLAY), 256, 0, stream>>>(w1, w1t, 64, 256);
  k_convT<<<dim3(64, LLAY), 256, 0, stream>>>(w2, w2t, 256, 64);
  k_convT<<<dim3((64 * CC + 255) / 256, 1), 256, 0, stream>>>(wout, woutt, 64, CC);

  k_embed<<<NTOK / 64, 512, 0, stream>>>(ex, labels, wet, be, lemb, wint, b_in, hh);

  for (int i = 0; i < LLAY; ++i) {
    k_pre<<<NTOK / 64, 512, 0, stream>>>(
        hh, mask, ln1s + i * DMM, ln1b + i * DMM,
        wqt + (size_t)i * DMM * DMM, bq + i * DMM,
        wkt + (size_t)i * DMM * DMM, bk + i * DMM,
        wvt + (size_t)i * DMM * DMM, bv + i * DMM,
        pqb, pkb, vvb);
    k_kv<<<BB * HH_ * NSPLIT, 256, 0, stream>>>(pkb, vvb, part);
    k_post<<<NTOK / 64, 512, 0, stream>>>(
        hh, mask, part, pqb,
        wot + (size_t)i * DMM * DMM, bo + i * DMM,
        ln2s + i * DMM, ln2b + i * DMM,
        w1t + (size_t)i * DMM * FFF, b1 + i * FFF,
        w2t + (size_t)i * FFF * DMM, b2 + i * DMM);
  }

  k_final<<<NTOK / 64, 512, 0, stream>>>(
      hh, mask, lnfs, lnfb, woutt, bout, (float*)d_out);
}

// Round 3
// 1112.313 us; speedup vs baseline: 1.3429x; 1.1661x over previous
//
#include <hip/hip_runtime.h>

#define BB 16
#define SS 4096
#define EE 128
#define DMM 64
#define HH_ 8
#define FFF 256
#define LLAY 8
#define CC 1623
#define NTOK (BB*SS)
#define PARTF (BB*HH_*72)   // floats per kv-part buffer

typedef __attribute__((ext_vector_type(8))) short bf8v;   // 8 bf16
typedef __attribute__((ext_vector_type(4))) short bf4v;   // 4 bf16
typedef __attribute__((ext_vector_type(4))) float f4;

__device__ __forceinline__ f4 MFMA(bf8v a, bf8v b, f4 c) {
  return __builtin_amdgcn_mfma_f32_16x16x32_bf16(a, b, c, 0, 0, 0);
}

__device__ __forceinline__ float bf2f(ushort u) {
  union { uint i; float f; } x; x.i = (uint)u << 16; return x.f;
}
__device__ __forceinline__ ushort f2bf(float f) {
  union { float f; uint i; } x; x.f = f;
  return (ushort)((x.i + 0x7fffu + ((x.i >> 16) & 1u)) >> 16);   // RNE
}

__device__ __forceinline__ void wave_stats(float v, float& mean, float& var) {
  float s = v, s2 = v * v;
  #pragma unroll
  for (int m = 32; m; m >>= 1) {
    s  += __shfl_xor(s,  m, 64);
    s2 += __shfl_xor(s2, m, 64);
  }
  mean = s * (1.0f / 64.0f);
  var  = s2 * (1.0f / 64.0f) - mean * mean;
}

__device__ __forceinline__ float gelu_tanh(float x) {
  float u = 0.7978845608028654f * (x + 0.044715f * x * x * x);
  float t = 1.0f - 2.0f / (__expf(2.0f * u) + 1.0f);
  return 0.5f * x * (1.0f + t);
}
__device__ __forceinline__ float phi_elu(float x) { return x > 0.0f ? x + 1.0f : __expf(x); }

// ---------------------------------------------------------------------------
// All weight conversions W[K][N] fp32 -> Wt[N][K] bf16 in one kernel.
// Also zeroes the 3 kv-part buffers (blocks 0..107).
// ---------------------------------------------------------------------------
struct ConvJobs {
  const float* src[9];
  ushort* dst[9];
  int KN[9];     // K*N per layer slice
  int N[9];
  int tot[9];    // K*N*layers
  int blk0[9];   // starting block id
};

__global__ __launch_bounds__(256) void k_convall(ConvJobs J, float* __restrict__ part)
{
  const int bid = blockIdx.x, tid = threadIdx.x;
  if (bid < 108) part[bid * 256 + tid] = 0.f;   // 3*PARTF = 27648 floats

  int j = 0;
  #pragma unroll
  for (int i = 1; i < 9; ++i) if (bid >= J.blk0[i]) j = i;
  int idx = (bid - J.blk0[j]) * 256 + tid;
  if (idx >= J.tot[j]) return;
  int kn = J.KN[j], n_ = J.N[j];
  int layer = idx / kn, rem = idx - layer * kn;
  int k = rem / n_, n = rem - k * n_;
  int K = kn / n_;
  J.dst[j][(size_t)layer * kn + (size_t)n * K + k] = f2bf(J.src[j][idx]);
}

// ---------------------------------------------------------------------------
// Shared pre-phase: LN1(hhL*mask) -> QKV -> phi -> pq(global, vectorized),
// pk/vv kept in LDS (token-major) -> block-local kv outer product ->
// atomicAdd into part_out. Called as the tail of k_embed_pre / k_layer.
// Caller must __syncthreads() after the last hhL write before calling.
// ---------------------------------------------------------------------------
__device__ __forceinline__ void pre_phase(
    int tid, int lane, int w, int t0,
    const float (*hhL)[64], const float* mk,
    ushort (*xbf)[72], ushort (*pqS)[72], ushort (*pkT)[72], ushort (*vvT)[72],
    const float* __restrict__ g1, const float* __restrict__ b1,
    const ushort* __restrict__ wqt, const float* __restrict__ bq,
    const ushort* __restrict__ wkt, const float* __restrict__ bk,
    const ushort* __restrict__ wvt, const float* __restrict__ bv,
    ushort* __restrict__ pq, float* __restrict__ part_out)
{
  // LN1 over masked hh
  #pragma unroll
  for (int m = 0; m < 8; ++m) {
    int t = w * 8 + m;
    float v = hhL[t][lane] * mk[t];
    float mean, var; wave_stats(v, mean, var);
    xbf[t][lane] = f2bf((v - mean) * rsqrtf(var + 1e-5f) * g1[lane] + b1[lane]);
  }
  __syncthreads();

  const int col = lane & 15, quad = lane >> 4;
  const int m0 = (w >> 1) * 16, nh = w & 1;

  bf8v a0 = *(const bf8v*)&xbf[m0 + col][quad * 8];
  bf8v a1 = *(const bf8v*)&xbf[m0 + col][32 + quad * 8];

  f4 accq[2], acck[2], accv[2];
  #pragma unroll
  for (int nt = 0; nt < 2; ++nt) {
    int nr = nh * 32 + nt * 16 + col;
    const ushort* bpq = wqt + (size_t)nr * 64 + quad * 8;
    const ushort* bpk = wkt + (size_t)nr * 64 + quad * 8;
    const ushort* bpv = wvt + (size_t)nr * 64 + quad * 8;
    f4 z = {0.f, 0.f, 0.f, 0.f};
    accq[nt] = MFMA(a1, *(const bf8v*)(bpq + 32), MFMA(a0, *(const bf8v*)bpq, z));
    acck[nt] = MFMA(a1, *(const bf8v*)(bpk + 32), MFMA(a0, *(const bf8v*)bpk, z));
    accv[nt] = MFMA(a1, *(const bf8v*)(bpv + 32), MFMA(a0, *(const bf8v*)bpv, z));
  }
  #pragma unroll
  for (int nt = 0; nt < 2; ++nt) {
    int c = nh * 32 + nt * 16 + col;
    float bqv = bq[c], bkv = bk[c], bvv = bv[c];
    #pragma unroll
    for (int r = 0; r < 4; ++r) {
      int tl = m0 + quad * 4 + r;
      pqS[tl][c] = f2bf(phi_elu(accq[nt][r] + bqv));
      pkT[c][tl] = f2bf(phi_elu(acck[nt][r] + bkv) * mk[tl]);   // token-major, masked
      vvT[c][tl] = f2bf(accv[nt][r] + bvv);                      // token-major
    }
  }
  __syncthreads();

  // pq -> global, 16B per thread (64 rows x 128B)
  {
    int row = tid >> 3, c8 = tid & 7;
    *(bf8v*)&pq[(size_t)(t0 + row) * DMM + c8 * 8] = *(const bf8v*)&pqS[row][c8 * 8];
  }

  // block-local kv: wave = head, lane = (d,e); kv[h][d][e] = sum_t pk[t][h8+d]*vv[t][h8+e]
  {
    const int h = w, d = lane >> 3, e = lane & 7;
    float kvacc = 0.f, ksacc = 0.f;
    const ushort* prow = &pkT[h * 8 + d][0];
    const ushort* vrow = &vvT[h * 8 + e][0];
    #pragma unroll
    for (int t4 = 0; t4 < 16; ++t4) {
      bf4v pk4 = *(const bf4v*)(prow + t4 * 4);
      bf4v vv4 = *(const bf4v*)(vrow + t4 * 4);
      #pragma unroll
      for (int i = 0; i < 4; ++i) {
        float pf = bf2f((ushort)pk4[i]);
        kvacc += pf * bf2f((ushort)vv4[i]);
        if (e == 0) ksacc += pf;
      }
    }
    const int bi = t0 >> 12;
    float* base = part_out + (size_t)(bi * HH_ + h) * 72;
    atomicAdd(base + d * 8 + e, kvacc);
    if (e == 0) atomicAdd(base + 64 + d, ksacc);
  }
}

// ---------------------------------------------------------------------------
// A: hh = (ex@we + be + lemb[labels]) @ w_in + b_in ; then pre(0) + kv(0)
// ---------------------------------------------------------------------------
__global__ __launch_bounds__(512) void k_embed_pre(
    const float* __restrict__ ex, const int* __restrict__ labels,
    const ushort* __restrict__ wet, const float* __restrict__ be,
    const float* __restrict__ lemb, const ushort* __restrict__ wint,
    const float* __restrict__ b_in, const float* __restrict__ mask,
    float* __restrict__ hh,
    const float* __restrict__ g1, const float* __restrict__ b1,
    const ushort* __restrict__ wqt, const float* __restrict__ bq,
    const ushort* __restrict__ wkt, const float* __restrict__ bk,
    const ushort* __restrict__ wvt, const float* __restrict__ bv,
    ushort* __restrict__ pq, float* __restrict__ part_out)
{
  __shared__ __align__(16) union {
    struct { ushort exL[64][136]; ushort embL[64][136]; } e;
    struct { ushort xbf[64][72], pqS[64][72], pkT[64][72], vvT[64][72]; } b;
  } U;
  __shared__ __align__(16) float hhL[64][64];
  __shared__ float mk[64];
  __shared__ int labL[64];

  const int tid = threadIdx.x, lane = tid & 63, w = tid >> 6;
  const int t0 = blockIdx.x * 64;

  if (tid < 64) { labL[tid] = labels[t0 + tid]; mk[tid] = mask[t0 + tid]; }
  #pragma unroll
  for (int i = 0; i < 16; ++i) {
    int idx = tid + 512 * i;
    int t = idx >> 7, k = idx & 127;
    U.e.exL[t][k] = f2bf(ex[(size_t)(t0 + t) * EE + k]);
  }
  __syncthreads();

  const int col = lane & 15, quad = lane >> 4;
  const int m0 = (w >> 1) * 16, nh = w & 1;

  {
    bf8v a[4];
    #pragma unroll
    for (int kf = 0; kf < 4; ++kf)
      a[kf] = *(const bf8v*)&U.e.exL[m0 + col][kf * 32 + quad * 8];
    #pragma unroll
    for (int nt = 0; nt < 4; ++nt) {
      int n0 = nh * 64 + nt * 16;
      const ushort* bp = wet + (size_t)(n0 + col) * 128 + quad * 8;
      f4 acc = {0.f, 0.f, 0.f, 0.f};
      #pragma unroll
      for (int kf = 0; kf < 4; ++kf)
        acc = MFMA(a[kf], *(const bf8v*)(bp + kf * 32), acc);
      int c = n0 + col;
      float bev = be[c];
      #pragma unroll
      for (int r = 0; r < 4; ++r) {
        int tl = m0 + quad * 4 + r;
        U.e.embL[tl][c] = f2bf(acc[r] + bev + lemb[(size_t)labL[tl] * EE + c]);
      }
    }
  }
  __syncthreads();

  {
    bf8v a[4];
    #pragma unroll
    for (int kf = 0; kf < 4; ++kf)
      a[kf] = *(const bf8v*)&U.e.embL[m0 + col][kf * 32 + quad * 8];
    #pragma unroll
    for (int nt = 0; nt < 2; ++nt) {
      int n0 = nh * 32 + nt * 16;
      const ushort* bp = wint + (size_t)(n0 + col) * 128 + quad * 8;
      f4 acc = {0.f, 0.f, 0.f, 0.f};
      #pragma unroll
      for (int kf = 0; kf < 4; ++kf)
        acc = MFMA(a[kf], *(const bf8v*)(bp + kf * 32), acc);
      int c = n0 + col;
      float biv = b_in[c];
      #pragma unroll
      for (int r = 0; r < 4; ++r) {
        int tl = m0 + quad * 4 + r;
        float val = acc[r] + biv;
        hhL[tl][c] = val;
        hh[(size_t)(t0 + tl) * DMM + c] = val;
      }
    }
  }
  __syncthreads();

  pre_phase(tid, lane, w, t0, hhL, mk,
            U.b.xbf, U.b.pqS, U.b.pkT, U.b.vvT,
            g1, b1, wqt, bq, wkt, bk, wvt, bv, pq, part_out);
}

// ---------------------------------------------------------------------------
// B: post(j) [att, wo+res, LN2, FFN, res, hh write] + pre(j+1) + kv(j+1).
// Also zeroes part_zero (the buffer layer j+2 will accumulate into).
// ---------------------------------------------------------------------------
__global__ __launch_bounds__(512) void k_layer(
    float* __restrict__ hh, const float* __restrict__ mask,
    const float* __restrict__ part_in, float* __restrict__ part_out,
    float* __restrict__ part_zero,
    ushort* __restrict__ pq,
    const ushort* __restrict__ wot, const float* __restrict__ bo,
    const float* __restrict__ g2, const float* __restrict__ b2ln,
    const ushort* __restrict__ w1t, const float* __restrict__ b1f,
    const ushort* __restrict__ w2t, const float* __restrict__ b2f,
    const float* __restrict__ g1n, const float* __restrict__ b1n,
    const ushort* __restrict__ wqt, const float* __restrict__ bq,
    const ushort* __restrict__ wkt, const float* __restrict__ bk,
    const ushort* __restrict__ wvt, const float* __restrict__ bv)
{
  __shared__ __align__(16) union UU {
    struct { float pqL[64][64]; ushort attbf[64][72]; } a;
    ushort tfL[64][264];
    struct { ushort xbf[64][72], pqS[64][72], pkT[64][72], vvT[64][72]; } b;
  } U;
  __shared__ __align__(16) float hhL[64][64];
  __shared__ ushort ybf[64][72];
  __shared__ float kvL[8][72];
  __shared__ float mk[64];

  const int tid = threadIdx.x, lane = tid & 63, w = tid >> 6;
  const int t0 = blockIdx.x * 64;
  const int bi = t0 >> 12;

  if (tid < 9) part_zero[(size_t)blockIdx.x * 9 + tid] = 0.f;

  // phase0: kvL, pqL, hhL(=hh*mask), mk
  for (int r = tid; r < 576; r += 512) {
    int h = r / 72, rr = r - h * 72;
    kvL[h][rr] = part_in[(size_t)(bi * HH_ + h) * 72 + rr];
  }
  {
    int t = tid >> 3, k8 = tid & 7;
    bf8v pv = *(const bf8v*)&pq[(size_t)(t0 + t) * DMM + k8 * 8];
    #pragma unroll
    for (int i = 0; i < 8; ++i) U.a.pqL[t][k8 * 8 + i] = bf2f((ushort)pv[i]);
  }
  #pragma unroll
  for (int it = 0; it < 2; ++it) {
    int idx = tid + it * 512;
    int row = idx >> 4, c4 = (idx & 15) * 4;
    float mv = mask[t0 + row];
    f4 hv = *(const f4*)&hh[(size_t)(t0 + row) * DMM + c4];
    hv *= mv;
    *(f4*)&hhL[row][c4] = hv;
    if ((idx & 15) == 0) mk[row] = mv;
  }
  __syncthreads();

  // phase1: att = (pq@kv)/(pq.ksum+eps)
  {
    const int j = lane, h2 = j >> 3, e = j & 7;
    #pragma unroll
    for (int m = 0; m < 8; ++m) {
      int t = w * 8 + m;
      float num = 0.f, den = 1e-6f;
      #pragma unroll
      for (int d = 0; d < 8; ++d) {
        float p = U.a.pqL[t][h2 * 8 + d];
        num += p * kvL[h2][d * 8 + e];
        den += p * kvL[h2][64 + d];
      }
      U.a.attbf[t][j] = f2bf(num / den);
    }
  }
  __syncthreads();

  const int col = lane & 15, quad = lane >> 4;
  const int m0 = (w >> 1) * 16, nh = w & 1;

  // phase2: att @ wo + residual -> hhL
  {
    bf8v a0 = *(const bf8v*)&U.a.attbf[m0 + col][quad * 8];
    bf8v a1 = *(const bf8v*)&U.a.attbf[m0 + col][32 + quad * 8];
    #pragma unroll
    for (int nt = 0; nt < 2; ++nt) {
      int c = nh * 32 + nt * 16 + col;
      const ushort* bp = wot + (size_t)c * 64 + quad * 8;
      f4 z = {0.f, 0.f, 0.f, 0.f};
      f4 acc = MFMA(a1, *(const bf8v*)(bp + 32), MFMA(a0, *(const bf8v*)bp, z));
      float bov = bo[c];
      #pragma unroll
      for (int r = 0; r < 4; ++r) {
        int tl = m0 + quad * 4 + r;
        hhL[tl][c] += acc[r] + bov;
      }
    }
  }
  __syncthreads();

  // phase3: LN2
  #pragma unroll
  for (int m = 0; m < 8; ++m) {
    int t = w * 8 + m;
    float v = hhL[t][lane];
    float mean, var; wave_stats(v, mean, var);
    ybf[t][lane] = f2bf((v - mean) * rsqrtf(var + 1e-5f) * g2[lane] + b2ln[lane]);
  }
  __syncthreads();

  // phase4: FFN1 + gelu -> tfL
  {
    bf8v a0 = *(const bf8v*)&ybf[m0 + col][quad * 8];
    bf8v a1 = *(const bf8v*)&ybf[m0 + col][32 + quad * 8];
    #pragma unroll
    for (int nt = 0; nt < 8; ++nt) {
      int c = nh * 128 + nt * 16 + col;
      const ushort* bp = w1t + (size_t)c * 64 + quad * 8;
      f4 z = {0.f, 0.f, 0.f, 0.f};
      f4 acc = MFMA(a1, *(const bf8v*)(bp + 32), MFMA(a0, *(const bf8v*)bp, z));
      float b1v = b1f[c];
      #pragma unroll
      for (int r = 0; r < 4; ++r)
        U.tfL[m0 + quad * 4 + r][c] = f2bf(gelu_tanh(acc[r] + b1v));
    }
  }
  __syncthreads();

  // phase5: FFN2 + residual -> hhL
  {
    bf8v af[8];
    #pragma unroll
    for (int kf = 0; kf < 8; ++kf)
      af[kf] = *(const bf8v*)&U.tfL[m0 + col][kf * 32 + quad * 8];
    #pragma unroll
    for (int nt = 0; nt < 2; ++nt) {
      int c = nh * 32 + nt * 16 + col;
      const ushort* bp = w2t + (size_t)c * 256 + quad * 8;
      f4 acc = {0.f, 0.f, 0.f, 0.f};
      #pragma unroll
      for (int kf = 0; kf < 8; ++kf)
        acc = MFMA(af[kf], *(const bf8v*)(bp + kf * 32), acc);
      float b2v = b2f[c];
      #pragma unroll
      for (int r = 0; r < 4; ++r) {
        int tl = m0 + quad * 4 + r;
        hhL[tl][c] += acc[r] + b2v;
      }
    }
  }
  __syncthreads();

  // hh -> global (vectorized 16B, wave = 1KB contiguous)
  #pragma unroll
  for (int it = 0; it < 2; ++it) {
    int idx = tid + it * 512;
    int row = idx >> 4, c4 = (idx & 15) * 4;
    *(f4*)&hh[(size_t)(t0 + row) * DMM + c4] = *(const f4*)&hhL[row][c4];
  }

  // pre(j+1) + kv(j+1)
  pre_phase(tid, lane, w, t0, hhL, mk,
            U.b.xbf, U.b.pqS, U.b.pkT, U.b.vvT,
            g1n, b1n, wqt, bq, wkt, bk, wvt, bv, pq, part_out);
}

// ---------------------------------------------------------------------------
// C: post(7) + LNf + logits (LDS-staged output stores)
// ---------------------------------------------------------------------------
__global__ __launch_bounds__(512) void k_lastpost(
    const float* __restrict__ hh, const float* __restrict__ mask,
    const float* __restrict__ part_in, const ushort* __restrict__ pq,
    const ushort* __restrict__ wot, const float* __restrict__ bo,
    const float* __restrict__ g2, const float* __restrict__ b2ln,
    const ushort* __restrict__ w1t, const float* __restrict__ b1f,
    const ushort* __restrict__ w2t, const float* __restrict__ b2f,
    const float* __restrict__ gf, const float* __restrict__ bfn,
    const ushort* __restrict__ woutt, const float* __restrict__ bout,
    float* __restrict__ out)
{
  __shared__ __align__(16) union UU {
    struct { float pqL[64][64]; ushort attbf[64][72]; } a;
    ushort tfL[64][264];
    float outL[64][132];
  } U;
  __shared__ __align__(16) float hhL[64][64];
  __shared__ ushort ybf[64][72];
  __shared__ float kvL[8][72];
  __shared__ float mk[64];

  const int tid = threadIdx.x, lane = tid & 63, w = tid >> 6;
  const int t0 = blockIdx.x * 64;
  const int bi = t0 >> 12;

  // phase0
  for (int r = tid; r < 576; r += 512) {
    int h = r / 72, rr = r - h * 72;
    kvL[h][rr] = part_in[(size_t)(bi * HH_ + h) * 72 + rr];
  }
  {
    int t = tid >> 3, k8 = tid & 7;
    bf8v pv = *(const bf8v*)&pq[(size_t)(t0 + t) * DMM + k8 * 8];
    #pragma unroll
    for (int i = 0; i < 8; ++i) U.a.pqL[t][k8 * 8 + i] = bf2f((ushort)pv[i]);
  }
  #pragma unroll
  for (int it = 0; it < 2; ++it) {
    int idx = tid + it * 512;
    int row = idx >> 4, c4 = (idx & 15) * 4;
    float mv = mask[t0 + row];
    f4 hv = *(const f4*)&hh[(size_t)(t0 + row) * DMM + c4];
    hv *= mv;
    *(f4*)&hhL[row][c4] = hv;
    if ((idx & 15) == 0) mk[row] = mv;
  }
  __syncthreads();

  // phase1: att
  {
    const int j = lane, h2 = j >> 3, e = j & 7;
    #pragma unroll
    for (int m = 0; m < 8; ++m) {
      int t = w * 8 + m;
      float num = 0.f, den = 1e-6f;
      #pragma unroll
      for (int d = 0; d < 8; ++d) {
        float p = U.a.pqL[t][h2 * 8 + d];
        num += p * kvL[h2][d * 8 + e];
        den += p * kvL[h2][64 + d];
      }
      U.a.attbf[t][j] = f2bf(num / den);
    }
  }
  __syncthreads();

  const int col = lane & 15, quad = lane >> 4;
  const int m0 = (w >> 1) * 16, nh = w & 1;

  // phase2: att @ wo + residual
  {
    bf8v a0 = *(const bf8v*)&U.a.attbf[m0 + col][quad * 8];
    bf8v a1 = *(const bf8v*)&U.a.attbf[m0 + col][32 + quad * 8];
    #pragma unroll
    for (int nt = 0; nt < 2; ++nt) {
      int c = nh * 32 + nt * 16 + col;
      const ushort* bp = wot + (size_t)c * 64 + quad * 8;
      f4 z = {0.f, 0.f, 0.f, 0.f};
      f4 acc = MFMA(a1, *(const bf8v*)(bp + 32), MFMA(a0, *(const bf8v*)bp, z));
      float bov = bo[c];
      #pragma unroll
      for (int r = 0; r < 4; ++r) {
        int tl = m0 + quad * 4 + r;
        hhL[tl][c] += acc[r] + bov;
      }
    }
  }
  __syncthreads();

  // phase3: LN2
  #pragma unroll
  for (int m = 0; m < 8; ++m) {
    int t = w * 8 + m;
    float v = hhL[t][lane];
    float mean, var; wave_stats(v, mean, var);
    ybf[t][lane] = f2bf((v - mean) * rsqrtf(var + 1e-5f) * g2[lane] + b2ln[lane]);
  }
  __syncthreads();

  // phase4: FFN1 + gelu
  {
    bf8v a0 = *(const bf8v*)&ybf[m0 + col][quad * 8];
    bf8v a1 = *(const bf8v*)&ybf[m0 + col][32 + quad * 8];
    #pragma unroll
    for (int nt = 0; nt < 8; ++nt) {
      int c = nh * 128 + nt * 16 + col;
      const ushort* bp = w1t + (size_t)c * 64 + quad * 8;
      f4 z = {0.f, 0.f, 0.f, 0.f};
      f4 acc = MFMA(a1, *(const bf8v*)(bp + 32), MFMA(a0, *(const bf8v*)bp, z));
      float b1v = b1f[c];
      #pragma unroll
      for (int r = 0; r < 4; ++r)
        U.tfL[m0 + quad * 4 + r][c] = f2bf(gelu_tanh(acc[r] + b1v));
    }
  }
  __syncthreads();

  // phase5: FFN2 + residual -> hhL (hh global write skipped: dead)
  {
    bf8v af[8];
    #pragma unroll
    for (int kf = 0; kf < 8; ++kf)
      af[kf] = *(const bf8v*)&U.tfL[m0 + col][kf * 32 + quad * 8];
    #pragma unroll
    for (int nt = 0; nt < 2; ++nt) {
      int c = nh * 32 + nt * 16 + col;
      const ushort* bp = w2t + (size_t)c * 256 + quad * 8;
      f4 acc = {0.f, 0.f, 0.f, 0.f};
      #pragma unroll
      for (int kf = 0; kf < 8; ++kf)
        acc = MFMA(af[kf], *(const bf8v*)(bp + kf * 32), acc);
      float b2v = b2f[c];
      #pragma unroll
      for (int r = 0; r < 4; ++r) {
        int tl = m0 + quad * 4 + r;
        hhL[tl][c] += acc[r] + b2v;
      }
    }
  }
  __syncthreads();

  // LNf * mask -> ybf
  #pragma unroll
  for (int m = 0; m < 8; ++m) {
    int t = w * 8 + m;
    float v = hhL[t][lane];
    float mean, var; wave_stats(v, mean, var);
    ybf[t][lane] = f2bf(((v - mean) * rsqrtf(var + 1e-5f) * gf[lane] + bfn[lane]) * mk[t]);
  }
  __syncthreads();

  bf8v a0[4], a1[4];
  #pragma unroll
  for (int mt = 0; mt < 4; ++mt) {
    a0[mt] = *(const bf8v*)&ybf[mt * 16 + col][quad * 8];
    a1[mt] = *(const bf8v*)&ybf[mt * 16 + col][32 + quad * 8];
  }

  // logits: 102 col-tiles of 16; 8 tiles (128 cols) per group, 13 groups
  for (int g = 0; g < 13; ++g) {
    int tile = g * 8 + w;
    if (tile < 102) {
      int c = tile * 16 + col;
      int cr = c < CC ? c : CC - 1;
      const ushort* bp = woutt + (size_t)cr * 64 + quad * 8;
      bf8v b0 = *(const bf8v*)bp;
      bf8v b1 = *(const bf8v*)(bp + 32);
      float bov = bout[cr];
      #pragma unroll
      for (int mt = 0; mt < 4; ++mt) {
        f4 z = {0.f, 0.f, 0.f, 0.f};
        f4 acc = MFMA(a1[mt], b1, MFMA(a0[mt], b0, z));
        #pragma unroll
        for (int r = 0; r < 4; ++r)
          U.outL[mt * 16 + quad * 4 + r][w * 16 + col] = acc[r] + bov;
      }
    }
    __syncthreads();

    const int c0 = g * 128;
    int nc = CC - c0; if (nc > 128) nc = 128;
    #pragma unroll
    for (int it = 0; it < 16; ++it) {
      int idx = tid + it * 512;
      int row = idx >> 7, cc = idx & 127;
      if (cc < nc)
        out[(size_t)(t0 + row) * CC + c0 + cc] = U.outL[row][cc];
    }
    __syncthreads();
  }
}

// ---------------------------------------------------------------------------

extern "C" void kernel_launch(void* const* d_in, const int* in_sizes, int n_in,
                              void* d_out, int out_size, void* d_ws, size_t ws_size,
                              hipStream_t stream) {
  (void)in_sizes; (void)n_in; (void)out_size; (void)ws_size;
  const float* ex    = (const float*)d_in[0];
  const int*   labels= (const int*)  d_in[1];
  const float* mask  = (const float*)d_in[2];
  const float* we    = (const float*)d_in[3];
  const float* be    = (const float*)d_in[4];
  const float* lemb  = (const float*)d_in[5];
  const float* w_in  = (const float*)d_in[6];
  const float* b_in  = (const float*)d_in[7];
  const float* ln1s  = (const float*)d_in[8];
  const float* ln1b  = (const float*)d_in[9];
  const float* wq    = (const float*)d_in[10];
  const float* bq    = (const float*)d_in[11];
  const float* wk    = (const float*)d_in[12];
  const float* bk    = (const float*)d_in[13];
  const float* wv    = (const float*)d_in[14];
  const float* bv    = (const float*)d_in[15];
  const float* wo    = (const float*)d_in[16];
  const float* bo    = (const float*)d_in[17];
  const float* ln2s  = (const float*)d_in[18];
  const float* ln2b  = (const float*)d_in[19];
  const float* w1    = (const float*)d_in[20];
  const float* b1    = (const float*)d_in[21];
  const float* w2    = (const float*)d_in[22];
  const float* b2    = (const float*)d_in[23];
  const float* lnfs  = (const float*)d_in[24];
  const float* lnfb  = (const float*)d_in[25];
  const float* wout  = (const float*)d_in[26];
  const float* bout  = (const float*)d_in[27];

  char* p = (char*)d_ws;
  float*  hh   = (float*)p;  p += (size_t)NTOK * DMM * 4;
  ushort* pqb  = (ushort*)p; p += (size_t)NTOK * DMM * 2;
  float*  part = (float*)p;  p += (size_t)3 * PARTF * 4;
  ushort* wet  = (ushort*)p; p += 128 * 128 * 2;
  ushort* wint = (ushort*)p; p += 64 * 128 * 2;
  ushort* wqt  = (ushort*)p; p += (size_t)LLAY * 64 * 64 * 2;
  ushort* wkt  = (ushort*)p; p += (size_t)LLAY * 64 * 64 * 2;
  ushort* wvt  = (ushort*)p; p += (size_t)LLAY * 64 * 64 * 2;
  ushort* wot  = (ushort*)p; p += (size_t)LLAY * 64 * 64 * 2;
  ushort* w1t  = (ushort*)p; p += (size_t)LLAY * 64 * 256 * 2;
  ushort* w2t  = (ushort*)p; p += (size_t)LLAY * 256 * 64 * 2;
  ushort* woutt= (ushort*)p; p += (size_t)64 * CC * 2;

  // fused weight conversion + part zeroing
  ConvJobs J;
  {
    const float* srcs[9] = {we, w_in, wq, wk, wv, wo, w1, w2, wout};
    ushort* dsts[9]      = {wet, wint, wqt, wkt, wvt, wot, w1t, w2t, woutt};
    const int Ks[9] = {128, 128, 64, 64, 64, 64, 64, 256, 64};
    const int Ns[9] = {128, 64, 64, 64, 64, 64, 256, 64, CC};
    const int Ls[9] = {1, 1, LLAY, LLAY, LLAY, LLAY, LLAY, LLAY, 1};
    int blk = 0;
    for (int j = 0; j < 9; ++j) {
      J.src[j] = srcs[j]; J.dst[j] = dsts[j];
      int kn = Ks[j] * Ns[j];
      J.KN[j] = kn; J.N[j] = Ns[j]; J.tot[j] = kn * Ls[j]; J.blk0[j] = blk;
      blk += (J.tot[j] + 255) / 256;
    }
    k_convall<<<blk, 256, 0, stream>>>(J, part);
  }

  // embed + pre(0) + kv(0) -> part[0]
  k_embed_pre<<<NTOK / 64, 512, 0, stream>>>(
      ex, labels, wet, be, lemb, wint, b_in, mask, hh,
      ln1s, ln1b, wqt, bq, wkt, bk, wvt, bv, pqb, part);

  // layers 0..6: post(j) + pre(j+1) + kv(j+1)
  for (int j = 0; j < LLAY - 1; ++j) {
    k_layer<<<NTOK / 64, 512, 0, stream>>>(
        hh, mask,
        part + (size_t)(j % 3) * PARTF,
        part + (size_t)((j + 1) % 3) * PARTF,
        part + (size_t)((j + 2) % 3) * PARTF,
        pqb,
        wot + (size_t)j * DMM * DMM, bo + j * DMM,
        ln2s + j * DMM, ln2b + j * DMM,
        w1t + (size_t)j * DMM * FFF, b1 + j * FFF,
        w2t + (size_t)j * FFF * DMM, b2 + j * DMM,
        ln1s + (j + 1) * DMM, ln1b + (j + 1) * DMM,
        wqt + (size_t)(j + 1) * DMM * DMM, bq + (j + 1) * DMM,
        wkt + (size_t)(j + 1) * DMM * DMM, bk + (j + 1) * DMM,
        wvt + (size_t)(j + 1) * DMM * DMM, bv + (j + 1) * DMM);
  }

  // post(7) + LNf + logits
  k_lastpost<<<NTOK / 64, 512, 0, stream>>>(
      hh, mask, part + (size_t)((LLAY - 1) % 3) * PARTF, pqb,
      wot + (size_t)(LLAY - 1) * DMM * DMM, bo + (LLAY - 1) * DMM,
      ln2s + (LLAY - 1) * DMM, ln2b + (LLAY - 1) * DMM,
      w1t + (size_t)(LLAY - 1) * DMM * FFF, b1 + (LLAY - 1) * FFF,
      w2t + (size_t)(LLAY - 1) * FFF * DMM, b2 + (LLAY - 1) * DMM,
      lnfs, lnfb, woutt, bout, (float*)d_out);
}